// Round 3
// baseline (140.228 us; speedup 1.0000x reference)
//
#include <hip/hip_runtime.h>
#include <cmath>

#define Bn 8
#define Tn 2048
#define Cn 1024
#define Kn 128

typedef __attribute__((ext_vector_type(8))) short short8;
typedef __attribute__((ext_vector_type(4))) float f32x4;
typedef unsigned short u16;
typedef unsigned int u32;

#define NEGINF (-__builtin_huge_valf())

__device__ __forceinline__ u16 f2b(float f) {
    u32 u = __float_as_uint(f);
    u32 r = (u + 0x7FFFu + ((u >> 16) & 1u)) >> 16;
    return (u16)r;
}
__device__ __forceinline__ float b2f(u16 v) {
    u32 u = ((u32)v) << 16;
    return __uint_as_float(u);
}

__device__ __forceinline__ void load_lds16(const u16* g, u16* l) {
    __builtin_amdgcn_global_load_lds(
        (const __attribute__((address_space(1))) u32*)(g),
        (__attribute__((address_space(3))) u32*)(l), 16, 0, 0);
}

// ---------------------------------------------------------------------------
// prep: W [1024 c][128 n] fp32 -> W^T bf16 [3][128 n][1024 c]
// ---------------------------------------------------------------------------
__global__ __launch_bounds__(256)
void prep_kernel(const float* __restrict__ Wq, const float* __restrict__ Wk,
                 const float* __restrict__ Wv, u16* __restrict__ Wt)
{
    int id = blockIdx.x * 256 + threadIdx.x;      // 0 .. 98303
    int w   = id >> 15;
    int rem = id & 32767;
    int c   = rem >> 5;
    int n4  = (rem & 31) << 2;
    const float* W = (w == 0) ? Wq : (w == 1) ? Wk : Wv;
    float4 v = *(const float4*)(W + (size_t)c * Kn + n4);
    u16* dst = Wt + (size_t)w * Kn * Cn;
    dst[(size_t)(n4 + 0) * Cn + c] = f2b(v.x);
    dst[(size_t)(n4 + 1) * Cn + c] = f2b(v.y);
    dst[(size_t)(n4 + 2) * Cn + c] = f2b(v.z);
    dst[(size_t)(n4 + 3) * Cn + c] = f2b(v.w);
}

// ---------------------------------------------------------------------------
// proj: qkv[w] = x @ W[w], bf16 MFMA. 128x128 tile, 4 waves of 64x64, BK=64.
// Block mapping: the 3 w-variants of one row-tile land on the SAME XCD
// (bids differ by 8) so x is read from HBM once, then L2-hit.
// ---------------------------------------------------------------------------
__global__ __launch_bounds__(256)
void proj_kernel(const float* __restrict__ x, const u16* __restrict__ Wt,
                 u16* __restrict__ qkv)
{
    const int bid = blockIdx.x;
    const int g8  = bid >> 3, xr = bid & 7;
    const int w   = g8 % 3;
    const int rt  = (g8 / 3) * 8 + xr;            // 0..127
    const u16* wtg = Wt + (size_t)w * Kn * Cn;    // [128 n][1024 c]
    u16* outp = qkv + (size_t)w * Bn * Tn * Kn;
    const int row0 = rt * 128;
    const int tid  = threadIdx.x;
    const int lane = tid & 63;
    const int wid  = tid >> 6;
    const int l15  = lane & 15, lh = lane >> 4;
    const int wm0 = (wid >> 1) * 64, wn0 = (wid & 1) * 64;

    __shared__ u16 xs[128][72];
    __shared__ u16 wt[128][72];

    f32x4 acc[4][4];
    #pragma unroll
    for (int i = 0; i < 4; ++i)
        #pragma unroll
        for (int j = 0; j < 4; ++j) acc[i][j] = (f32x4){0.f, 0.f, 0.f, 0.f};

    for (int kk = 0; kk < Cn; kk += 64) {
        __syncthreads();
        #pragma unroll
        for (int i = 0; i < 8; ++i) {
            int idx = tid + i * 256;
            int r = idx >> 4, c4 = (idx & 15) << 2;
            float4 xv = *(const float4*)(x + (size_t)(row0 + r) * Cn + kk + c4);
            ushort4 pk = { f2b(xv.x), f2b(xv.y), f2b(xv.z), f2b(xv.w) };
            *(ushort4*)&xs[r][c4] = pk;
        }
        #pragma unroll
        for (int i = 0; i < 4; ++i) {
            int idx = tid + i * 256;
            int n = idx >> 3, c8 = (idx & 7) << 3;
            uint4 wv = *(const uint4*)(wtg + (size_t)n * Cn + kk + c8);
            *(uint4*)&wt[n][c8] = wv;
        }
        __syncthreads();
        #pragma unroll
        for (int kc = 0; kc < 2; ++kc) {
            const int coff = kc * 32 + lh * 8;
            short8 af[4], bf[4];
            #pragma unroll
            for (int mg = 0; mg < 4; ++mg)
                af[mg] = *(const short8*)&xs[wm0 + mg * 16 + l15][coff];
            #pragma unroll
            for (int ng = 0; ng < 4; ++ng)
                bf[ng] = *(const short8*)&wt[wn0 + ng * 16 + l15][coff];
            #pragma unroll
            for (int mg = 0; mg < 4; ++mg)
                #pragma unroll
                for (int ng = 0; ng < 4; ++ng)
                    acc[mg][ng] = __builtin_amdgcn_mfma_f32_16x16x32_bf16(
                        af[mg], bf[ng], acc[mg][ng], 0, 0, 0);
        }
    }
    #pragma unroll
    for (int mg = 0; mg < 4; ++mg)
        #pragma unroll
        for (int ng = 0; ng < 4; ++ng)
            #pragma unroll
            for (int r = 0; r < 4; ++r) {
                int m = row0 + wm0 + mg * 16 + lh * 4 + r;
                int n = wn0 + ng * 16 + l15;
                outp[(size_t)m * Kn + n] = f2b(acc[mg][ng][r]);
            }
}

// ---------------------------------------------------------------------------
// attn: causal flash, split-s equal-work blocks.
// 256 blocks = 8 batches x 32 chunk-jobs; 8 warps x 32 q-rows (q-tile 256).
// Per super (64 s): K,V double-buffered in LDS (64KB), one barrier.
// Swapped QK^T (q lane-local), P via in-register shuffles, PV O^T=V^T P^T.
// Writes raw partial (O bf16, m/l fp32) per job slot; merge kernel combines.
// ---------------------------------------------------------------------------
__device__ const int g_job_qi[32] = {0, 1,1, 2,2,2, 3,3,3,3, 4,4,4,4,
                                     5,5,5,5,5, 6,6,6,6,6,6, 7,7,7,7,7,7,7};
__device__ const int g_sup_b[32] = {0, 0,4, 0,4,8, 0,4,8,12, 0,5,10,15,
                                    0,4,9,14,19, 0,4,9,14,18,23, 0,4,9,13,18,22,27};
__device__ const int g_sup_e[32] = {4, 4,8, 4,8,12, 4,8,12,16, 5,10,15,20,
                                    4,9,14,19,24, 4,9,14,18,23,28, 4,9,13,18,22,27,32};

__global__ __launch_bounds__(512, 2)
void attn_kernel(const u16* __restrict__ qg_, const u16* __restrict__ kg_,
                 const u16* __restrict__ vg_, u16* __restrict__ pO,
                 float* __restrict__ pM, float* __restrict__ pL)
{
    const int b   = blockIdx.x;                   // batch -> XCD b
    const int job = blockIdx.y;                   // 0..31
    const int qi  = g_job_qi[job];
    const int sb  = g_sup_b[job], se = g_sup_e[job];

    const u16* qw = qg_ + (size_t)b * Tn * Kn;
    const u16* kw = kg_ + (size_t)b * Tn * Kn;
    const u16* vw = vg_ + (size_t)b * Tn * Kn;

    const int tid  = threadIdx.x;
    const int lane = tid & 63;
    const int wid  = tid >> 6;                    // 0..7
    const int l15  = lane & 15, lh = lane >> 4;

    const int q0 = qi * 256 + wid * 32;           // warp's first q row (batch-local)
    const int qmax_w = q0 + 31;

    // LDS: K0 | K1 | V0 | V1, 16KB each (u16 units of 8192). 64KB total.
    __shared__ u16 lds[32768];

    // ---- Q fragments: B[k=c][n=q], lane holds Q[q0+g*16+l15][kc*32+lh*8+j]
    short8 qf[2][4];
    #pragma unroll
    for (int g = 0; g < 2; ++g)
        #pragma unroll
        for (int kc = 0; kc < 4; ++kc)
            qf[g][kc] = *(const short8*)(qw + (size_t)(q0 + g * 16 + l15) * Kn
                                         + kc * 32 + lh * 8);

    f32x4 acc[8][2];
    #pragma unroll
    for (int dt = 0; dt < 8; ++dt)
        #pragma unroll
        for (int g = 0; g < 2; ++g) acc[dt][g] = (f32x4){0.f, 0.f, 0.f, 0.f};
    float m_g[2] = {NEGINF, NEGINF}, l_g[2] = {0.f, 0.f};

    const float scale = 0.08838834764831843f;     // 1/sqrt(128)

    // ---- staging helpers ----
    auto stageK = [&](int sup, int buf) {
        const u16* src = kw + (size_t)sup * 64 * Kn;
        u16* dst = lds + buf * 8192;
        #pragma unroll
        for (int i = 0; i < 2; ++i) {
            int u = wid * 128 + i * 64 + lane;
            int row = u >> 4;
            int c16 = (u & 15) ^ (row & 7);       // source pre-swizzle
            load_lds16(src + (size_t)row * Kn + c16 * 8,
                       dst + (size_t)(wid * 128 + i * 64) * 8);
        }
    };
    auto loadV = [&](int sup, uint4* vr) {
        const u16* src = vw + (size_t)sup * 64 * Kn;
        #pragma unroll
        for (int r = 0; r < 2; ++r) {
            int s  = tid & 63;
            int u8 = (tid >> 6) + 8 * r;
            vr[r] = *(const uint4*)(src + (size_t)s * Kn + u8 * 8);
        }
    };
    auto writeV = [&](int buf, const uint4* vr) {
        u16* dst = lds + 16384 + buf * 8192;
        #pragma unroll
        for (int r = 0; r < 2; ++r) {
            int s  = tid & 63;
            int u8 = (tid >> 6) + 8 * r;
            const u16* e = (const u16*)&vr[r];
            #pragma unroll
            for (int j = 0; j < 8; ++j) {
                int d = u8 * 8 + j;               // d&7 == j
                dst[d * 64 + (((s >> 3) ^ j) << 3) + (s & 7)] = e[j];
            }
        }
    };

    // prologue: stage first super into buf 0
    uint4 vreg[2];
    stageK(sb, 0);
    loadV(sb, vreg);
    writeV(0, vreg);

    for (int sup = sb; sup < se; ++sup) {
        const int cur = (sup - sb) & 1;
        __syncthreads();                          // staging(cur) + prev compute done
        const bool have_next = (sup + 1 < se);
        if (have_next) {
            stageK(sup + 1, cur ^ 1);             // fire-and-forget (vmcnt)
            loadV(sup + 1, vreg);                 // issue early (T14)
        }
        if (sup * 64 <= qmax_w) {                 // warp active?
            const u16* Kb = lds + cur * 8192;
            const u16* Vb = lds + 16384 + cur * 8192;
            // ---- QK^T: S^T[s][q]
            f32x4 sf[4][2];
            #pragma unroll
            for (int mt = 0; mt < 4; ++mt)
                #pragma unroll
                for (int g = 0; g < 2; ++g) sf[mt][g] = (f32x4){0.f,0.f,0.f,0.f};
            #pragma unroll
            for (int kc = 0; kc < 4; ++kc) {
                short8 a[4];
                #pragma unroll
                for (int mt = 0; mt < 4; ++mt) {
                    int row = mt * 16 + l15;
                    int ch  = (kc * 4 + lh) ^ (row & 7);
                    a[mt] = *(const short8*)(Kb + row * 128 + ch * 8);
                }
                #pragma unroll
                for (int mt = 0; mt < 4; ++mt)
                    #pragma unroll
                    for (int g = 0; g < 2; ++g)
                        sf[mt][g] = __builtin_amdgcn_mfma_f32_16x16x32_bf16(
                            a[mt], qf[g][kc], sf[mt][g], 0, 0, 0);
            }
            // ---- mask + online softmax (q lane-local)
            const int sbase = sup * 64;
            u32 upk[2][4][2];
            float alpha_g[2];
            #pragma unroll
            for (int g = 0; g < 2; ++g) {
                const int qg = q0 + g * 16 + l15;
                float pv[16];
                float pm = NEGINF;
                #pragma unroll
                for (int mt = 0; mt < 4; ++mt)
                    #pragma unroll
                    for (int r = 0; r < 4; ++r) {
                        int sg = sbase + mt * 16 + lh * 4 + r;
                        float vv = sf[mt][g][r] * scale;
                        vv = (sg > qg) ? NEGINF : vv;
                        pv[mt * 4 + r] = vv;
                        pm = fmaxf(pm, vv);
                    }
                pm = fmaxf(pm, __shfl_xor(pm, 16));
                pm = fmaxf(pm, __shfl_xor(pm, 32));
                float mn  = fmaxf(m_g[g], pm);
                float mns = (mn == NEGINF) ? 0.f : mn;   // NaN guard
                float al  = __expf(m_g[g] - mns);
                m_g[g] = mn;
                alpha_g[g] = al;
                float ps = 0.f;
                #pragma unroll
                for (int i = 0; i < 16; ++i) { pv[i] = __expf(pv[i] - mns); ps += pv[i]; }
                ps += __shfl_xor(ps, 16);
                ps += __shfl_xor(ps, 32);
                l_g[g] = l_g[g] * al + ps;
                #pragma unroll
                for (int mt = 0; mt < 4; ++mt)
                    #pragma unroll
                    for (int h = 0; h < 2; ++h)
                        upk[g][mt][h] = (u32)f2b(pv[mt * 4 + 2 * h])
                                      | ((u32)f2b(pv[mt * 4 + 2 * h + 1]) << 16);
            }
            #pragma unroll
            for (int dt = 0; dt < 8; ++dt)
                #pragma unroll
                for (int g = 0; g < 2; ++g)
                    acc[dt][g] *= alpha_g[g];
            // ---- PV: O^T += V^T * P^T
            #pragma unroll
            for (int ks = 0; ks < 2; ++ks) {
                short8 pf[2];
                #pragma unroll
                for (int g = 0; g < 2; ++g) {
                    union { u32 w[4]; short8 v; } uu;
                    #pragma unroll
                    for (int hp = 0; hp < 4; ++hp) {
                        int srcLane = l15 + 16 * ((lh & 1) * 2 + (hp >> 1));
                        u32 vA = __shfl(upk[g][2 * ks][hp & 1], srcLane, 64);
                        u32 vB = __shfl(upk[g][2 * ks + 1][hp & 1], srcLane, 64);
                        uu.w[hp] = (lh < 2) ? vA : vB;
                    }
                    pf[g] = uu.v;
                }
                #pragma unroll
                for (int dt = 0; dt < 8; ++dt) {
                    int d  = dt * 16 + l15;
                    int ch = (ks * 4 + lh) ^ (d & 7);
                    short8 av = *(const short8*)(Vb + d * 64 + ch * 8);
                    #pragma unroll
                    for (int g = 0; g < 2; ++g)
                        acc[dt][g] = __builtin_amdgcn_mfma_f32_16x16x32_bf16(
                            av, pf[g], acc[dt][g], 0, 0, 0);
                }
            }
        }
        if (have_next) writeV(cur ^ 1, vreg);     // write late, before next barrier
    }

    // ---- epilogue: raw partials
    const size_t slotrow = ((size_t)b * 32 + job) * 256 + wid * 32;
    #pragma unroll
    for (int g = 0; g < 2; ++g) {
        size_t row = slotrow + g * 16 + l15;
        #pragma unroll
        for (int dt = 0; dt < 8; ++dt) {
            ushort4 o = { f2b(acc[dt][g][0]), f2b(acc[dt][g][1]),
                          f2b(acc[dt][g][2]), f2b(acc[dt][g][3]) };
            *(ushort4*)(pO + row * 128 + dt * 16 + lh * 4) = o;
        }
        if (lh == 0) {
            pM[row] = m_g[g];
            pL[row] = l_g[g];
        }
    }
}

// ---------------------------------------------------------------------------
// merge: combine <=8 chunk partials per q-row.
// ---------------------------------------------------------------------------
__device__ const int g_cnt[8] = {1, 2, 3, 4, 4, 5, 6, 7};
__device__ const int g_s0[8]  = {0, 1, 3, 6, 10, 14, 19, 25};

__global__ __launch_bounds__(256)
void merge_kernel(const u16* __restrict__ pO, const float* __restrict__ pM,
                  const float* __restrict__ pL, float* __restrict__ out)
{
    const int b  = blockIdx.x;        // 8
    const int qi = blockIdx.y;        // 8
    const int qr = blockIdx.z;        // 4
    const int c  = g_cnt[qi], s0 = g_s0[qi];
    const int tid = threadIdx.x;

    __shared__ float wsh[64][8];

    const int rbase = qr * 64;        // within 256-row q-tile
    if (tid < 64) {
        int row = rbase + tid;
        size_t mb = ((size_t)b * 32 + s0) * 256 + row;
        float M = NEGINF, mv[8];
        #pragma unroll
        for (int i = 0; i < 8; ++i)
            if (i < c) { mv[i] = pM[mb + (size_t)i * 256]; M = fmaxf(M, mv[i]); }
        float L = 0.f, w[8];
        #pragma unroll
        for (int i = 0; i < 8; ++i)
            if (i < c) {
                float e = __expf(mv[i] - M);
                L += pL[mb + (size_t)i * 256] * e;
                w[i] = e;
            }
        float invL = 1.f / L;
        #pragma unroll
        for (int i = 0; i < 8; ++i)
            if (i < c) wsh[tid][i] = w[i] * invL;
    }
    __syncthreads();

    const int d = tid & 127, half = tid >> 7;
    for (int j = 0; j < 32; ++j) {
        int rr  = half * 32 + j;
        int row = rbase + rr;
        size_t ob = (((size_t)b * 32 + s0) * 256 + row) * 128 + d;
        float o = 0.f;
        #pragma unroll
        for (int i = 0; i < 8; ++i)
            if (i < c) o += wsh[rr][i] * b2f(pO[ob + (size_t)i * 256 * 128]);
        out[((size_t)b * Tn + qi * 256 + row) * Kn + d] = o;
    }
}

// ---------------------------------------------------------------------------
extern "C" void kernel_launch(void* const* d_in, const int* in_sizes, int n_in,
                              void* d_out, int out_size, void* d_ws, size_t ws_size,
                              hipStream_t stream)
{
    const float* x  = (const float*)d_in[0];
    const float* Wq = (const float*)d_in[1];
    const float* Wk = (const float*)d_in[2];
    const float* Wv = (const float*)d_in[3];
    float* out = (float*)d_out;

    u16* ws = (u16*)d_ws;
    const size_t btk = (size_t)Bn * Tn * Kn;       // 2,097,152
    u16* q  = ws;
    u16* k  = ws + btk;
    u16* v  = ws + 2 * btk;
    u16* Wt = ws + 3 * btk;                        // 3*128*1024 = 393216 u16
    u16* pO = ws + 3 * btk + 393216;               // 8*32*256*128 = 8,388,608 u16
    float* pM = (float*)(pO + (size_t)8388608);    // 65536 f32
    float* pL = pM + 65536;                        // 65536 f32
    // total ws usage ~30.7 MB

    prep_kernel<<<384, 256, 0, stream>>>(Wq, Wk, Wv, Wt);
    proj_kernel<<<384, 256, 0, stream>>>(x, Wt, ws);
    attn_kernel<<<dim3(Bn, 32), 512, 0, stream>>>(q, k, v, pO, pM, pL);
    merge_kernel<<<dim3(Bn, 8, 4), 256, 0, stream>>>(pO, pM, pL, out);
}

// Round 4
// 75.434 us; speedup vs baseline: 1.8589x; 1.8589x over previous
//
#include <hip/hip_runtime.h>
#include <cmath>

#define Bn 8
#define Tn 2048
#define Cn 1024
#define Kn 128

typedef __attribute__((ext_vector_type(8))) short short8;
typedef __attribute__((ext_vector_type(4))) float f32x4;
typedef unsigned short u16;
typedef unsigned int u32;

#define NEGINF (-__builtin_huge_valf())

__device__ __forceinline__ u16 f2b(float f) {
    u32 u = __float_as_uint(f);
    u32 r = (u + 0x7FFFu + ((u >> 16) & 1u)) >> 16;
    return (u16)r;
}
__device__ __forceinline__ float b2f(u16 v) {
    u32 u = ((u32)v) << 16;
    return __uint_as_float(u);
}

__device__ __forceinline__ void load_lds16(const u16* g, u16* l) {
    __builtin_amdgcn_global_load_lds(
        (const __attribute__((address_space(1))) u32*)(g),
        (__attribute__((address_space(3))) u32*)(l), 16, 0, 0);
}

// ---------------------------------------------------------------------------
// prep: W [1024 c][128 n] fp32 -> W^T bf16 [3][128 n][1024 c]
// ---------------------------------------------------------------------------
__global__ __launch_bounds__(256)
void prep_kernel(const float* __restrict__ Wq, const float* __restrict__ Wk,
                 const float* __restrict__ Wv, u16* __restrict__ Wt)
{
    int id = blockIdx.x * 256 + threadIdx.x;      // 0 .. 98303
    int w   = id >> 15;
    int rem = id & 32767;
    int c   = rem >> 5;
    int n4  = (rem & 31) << 2;
    const float* W = (w == 0) ? Wq : (w == 1) ? Wk : Wv;
    float4 v = *(const float4*)(W + (size_t)c * Kn + n4);
    u16* dst = Wt + (size_t)w * Kn * Cn;
    dst[(size_t)(n4 + 0) * Cn + c] = f2b(v.x);
    dst[(size_t)(n4 + 1) * Cn + c] = f2b(v.y);
    dst[(size_t)(n4 + 2) * Cn + c] = f2b(v.z);
    dst[(size_t)(n4 + 3) * Cn + c] = f2b(v.w);
}

// ---------------------------------------------------------------------------
// proj: qkv[w] = x @ W[w], bf16 MFMA. 128x128 tile, 4 waves of 64x64, BK=64.
// Block mapping: the 3 w-variants of one row-tile land on the SAME XCD
// (bids differ by 8) so x is read from HBM once, then L2-hit.
// ---------------------------------------------------------------------------
__global__ __launch_bounds__(256)
void proj_kernel(const float* __restrict__ x, const u16* __restrict__ Wt,
                 u16* __restrict__ qkv)
{
    const int bid = blockIdx.x;
    const int g8  = bid >> 3, xr = bid & 7;
    const int w   = g8 % 3;
    const int rt  = (g8 / 3) * 8 + xr;            // 0..127
    const u16* wtg = Wt + (size_t)w * Kn * Cn;    // [128 n][1024 c]
    u16* outp = qkv + (size_t)w * Bn * Tn * Kn;
    const int row0 = rt * 128;
    const int tid  = threadIdx.x;
    const int lane = tid & 63;
    const int wid  = tid >> 6;
    const int l15  = lane & 15, lh = lane >> 4;
    const int wm0 = (wid >> 1) * 64, wn0 = (wid & 1) * 64;

    __shared__ u16 xs[128][72];
    __shared__ u16 wt[128][72];

    f32x4 acc[4][4];
    #pragma unroll
    for (int i = 0; i < 4; ++i)
        #pragma unroll
        for (int j = 0; j < 4; ++j) acc[i][j] = (f32x4){0.f, 0.f, 0.f, 0.f};

    for (int kk = 0; kk < Cn; kk += 64) {
        __syncthreads();
        #pragma unroll
        for (int i = 0; i < 8; ++i) {
            int idx = tid + i * 256;
            int r = idx >> 4, c4 = (idx & 15) << 2;
            float4 xv = *(const float4*)(x + (size_t)(row0 + r) * Cn + kk + c4);
            ushort4 pk = { f2b(xv.x), f2b(xv.y), f2b(xv.z), f2b(xv.w) };
            *(ushort4*)&xs[r][c4] = pk;
        }
        #pragma unroll
        for (int i = 0; i < 4; ++i) {
            int idx = tid + i * 256;
            int n = idx >> 3, c8 = (idx & 7) << 3;
            uint4 wv = *(const uint4*)(wtg + (size_t)n * Cn + kk + c8);
            *(uint4*)&wt[n][c8] = wv;
        }
        __syncthreads();
        #pragma unroll
        for (int kc = 0; kc < 2; ++kc) {
            const int coff = kc * 32 + lh * 8;
            short8 af[4], bf[4];
            #pragma unroll
            for (int mg = 0; mg < 4; ++mg)
                af[mg] = *(const short8*)&xs[wm0 + mg * 16 + l15][coff];
            #pragma unroll
            for (int ng = 0; ng < 4; ++ng)
                bf[ng] = *(const short8*)&wt[wn0 + ng * 16 + l15][coff];
            #pragma unroll
            for (int mg = 0; mg < 4; ++mg)
                #pragma unroll
                for (int ng = 0; ng < 4; ++ng)
                    acc[mg][ng] = __builtin_amdgcn_mfma_f32_16x16x32_bf16(
                        af[mg], bf[ng], acc[mg][ng], 0, 0, 0);
        }
    }
    #pragma unroll
    for (int mg = 0; mg < 4; ++mg)
        #pragma unroll
        for (int ng = 0; ng < 4; ++ng)
            #pragma unroll
            for (int r = 0; r < 4; ++r) {
                int m = row0 + wm0 + mg * 16 + lh * 4 + r;
                int n = wn0 + ng * 16 + l15;
                outp[(size_t)m * Kn + n] = f2b(acc[mg][ng][r]);
            }
}

// ---------------------------------------------------------------------------
// attn: causal flash, split-s equal-work blocks.
// 256 blocks = 8 batches x 32 chunk-jobs; 8 warps x 32 q-rows (q-tile 256).
// Per super (64 s): K,V double-buffered in LDS (64KB), one barrier.
// Swapped QK^T (q lane-local), P via in-register shuffles, PV O^T=V^T P^T.
// Writes raw partial (O bf16, m/l fp32) per job slot; merge kernel combines.
// ---------------------------------------------------------------------------
__device__ const int g_job_qi[32] = {0, 1,1, 2,2,2, 3,3,3,3, 4,4,4,4,
                                     5,5,5,5,5, 6,6,6,6,6,6, 7,7,7,7,7,7,7};
__device__ const int g_sup_b[32] = {0, 0,4, 0,4,8, 0,4,8,12, 0,5,10,15,
                                    0,4,9,14,19, 0,4,9,14,18,23, 0,4,9,13,18,22,27};
__device__ const int g_sup_e[32] = {4, 4,8, 4,8,12, 4,8,12,16, 5,10,15,20,
                                    4,9,14,19,24, 4,9,14,18,23,28, 4,9,13,18,22,27,32};

__global__ __launch_bounds__(512, 2)
void attn_kernel(const u16* __restrict__ qg_, const u16* __restrict__ kg_,
                 const u16* __restrict__ vg_, u16* __restrict__ pO,
                 float* __restrict__ pM, float* __restrict__ pL)
{
    const int b   = blockIdx.x;                   // batch -> XCD b
    const int job = blockIdx.y;                   // 0..31
    const int qi  = g_job_qi[job];
    const int sb  = g_sup_b[job], se = g_sup_e[job];

    const u16* qw = qg_ + (size_t)b * Tn * Kn;
    const u16* kw = kg_ + (size_t)b * Tn * Kn;
    const u16* vw = vg_ + (size_t)b * Tn * Kn;

    const int tid  = threadIdx.x;
    const int lane = tid & 63;
    const int wid  = tid >> 6;                    // 0..7
    const int l15  = lane & 15, lh = lane >> 4;

    const int q0 = qi * 256 + wid * 32;           // warp's first q row (batch-local)
    const int qmax_w = q0 + 31;

    // LDS: K0 | K1 | V0 | V1, 16KB each (u16 units of 8192). 64KB total.
    __shared__ u16 lds[32768];

    // ---- Q fragments: B[k=c][n=q], lane holds Q[q0+g*16+l15][kc*32+lh*8+j]
    short8 qf[2][4];
    #pragma unroll
    for (int g = 0; g < 2; ++g)
        #pragma unroll
        for (int kc = 0; kc < 4; ++kc)
            qf[g][kc] = *(const short8*)(qw + (size_t)(q0 + g * 16 + l15) * Kn
                                         + kc * 32 + lh * 8);

    f32x4 acc[8][2];
    #pragma unroll
    for (int dt = 0; dt < 8; ++dt)
        #pragma unroll
        for (int g = 0; g < 2; ++g) acc[dt][g] = (f32x4){0.f, 0.f, 0.f, 0.f};
    float m_g[2] = {NEGINF, NEGINF}, l_g[2] = {0.f, 0.f};

    const float scale = 0.08838834764831843f;     // 1/sqrt(128)

    // ---- staging helpers ----
    auto stageK = [&](int sup, int buf) {
        const u16* src = kw + (size_t)sup * 64 * Kn;
        u16* dst = lds + buf * 8192;
        #pragma unroll
        for (int i = 0; i < 2; ++i) {
            int u = wid * 128 + i * 64 + lane;
            int row = u >> 4;
            int c16 = (u & 15) ^ (row & 7);       // source pre-swizzle
            load_lds16(src + (size_t)row * Kn + c16 * 8,
                       dst + (size_t)(wid * 128 + i * 64) * 8);
        }
    };
    auto loadV = [&](int sup, uint4* vr) {
        const u16* src = vw + (size_t)sup * 64 * Kn;
        #pragma unroll
        for (int r = 0; r < 2; ++r) {
            int s  = tid & 63;
            int u8 = (tid >> 6) + 8 * r;
            vr[r] = *(const uint4*)(src + (size_t)s * Kn + u8 * 8);
        }
    };
    auto writeV = [&](int buf, const uint4* vr) {
        u16* dst = lds + 16384 + buf * 8192;
        #pragma unroll
        for (int r = 0; r < 2; ++r) {
            int s  = tid & 63;
            int u8 = (tid >> 6) + 8 * r;
            const u16* e = (const u16*)&vr[r];
            #pragma unroll
            for (int j = 0; j < 8; ++j) {
                int d = u8 * 8 + j;               // d&7 == j
                dst[d * 64 + (((s >> 3) ^ j) << 3) + (s & 7)] = e[j];
            }
        }
    };

    // prologue: stage first super into buf 0
    uint4 vreg[2];
    stageK(sb, 0);
    loadV(sb, vreg);
    writeV(0, vreg);

    for (int sup = sb; sup < se; ++sup) {
        const int cur = (sup - sb) & 1;
        __syncthreads();                          // staging(cur) + prev compute done
        const bool have_next = (sup + 1 < se);
        if (have_next) {
            stageK(sup + 1, cur ^ 1);             // fire-and-forget (vmcnt)
            loadV(sup + 1, vreg);                 // issue early (T14)
        }
        if (sup * 64 <= qmax_w) {                 // warp active?
            const u16* Kb = lds + cur * 8192;
            const u16* Vb = lds + 16384 + cur * 8192;
            // ---- QK^T: S^T[s][q]
            f32x4 sf[4][2];
            #pragma unroll
            for (int mt = 0; mt < 4; ++mt)
                #pragma unroll
                for (int g = 0; g < 2; ++g) sf[mt][g] = (f32x4){0.f,0.f,0.f,0.f};
            #pragma unroll
            for (int kc = 0; kc < 4; ++kc) {
                short8 a[4];
                #pragma unroll
                for (int mt = 0; mt < 4; ++mt) {
                    int row = mt * 16 + l15;
                    int ch  = (kc * 4 + lh) ^ (row & 7);
                    a[mt] = *(const short8*)(Kb + row * 128 + ch * 8);
                }
                #pragma unroll
                for (int mt = 0; mt < 4; ++mt)
                    #pragma unroll
                    for (int g = 0; g < 2; ++g)
                        sf[mt][g] = __builtin_amdgcn_mfma_f32_16x16x32_bf16(
                            a[mt], qf[g][kc], sf[mt][g], 0, 0, 0);
            }
            // ---- mask + online softmax (q lane-local)
            const int sbase = sup * 64;
            u32 upk[2][4][2];
            float alpha_g[2];
            #pragma unroll
            for (int g = 0; g < 2; ++g) {
                const int qg = q0 + g * 16 + l15;
                float pv[16];
                float pm = NEGINF;
                #pragma unroll
                for (int mt = 0; mt < 4; ++mt)
                    #pragma unroll
                    for (int r = 0; r < 4; ++r) {
                        int sg = sbase + mt * 16 + lh * 4 + r;
                        float vv = sf[mt][g][r] * scale;
                        vv = (sg > qg) ? NEGINF : vv;
                        pv[mt * 4 + r] = vv;
                        pm = fmaxf(pm, vv);
                    }
                pm = fmaxf(pm, __shfl_xor(pm, 16));
                pm = fmaxf(pm, __shfl_xor(pm, 32));
                float mn  = fmaxf(m_g[g], pm);
                float mns = (mn == NEGINF) ? 0.f : mn;   // NaN guard
                float al  = __expf(m_g[g] - mns);
                m_g[g] = mn;
                alpha_g[g] = al;
                float ps = 0.f;
                #pragma unroll
                for (int i = 0; i < 16; ++i) { pv[i] = __expf(pv[i] - mns); ps += pv[i]; }
                ps += __shfl_xor(ps, 16);
                ps += __shfl_xor(ps, 32);
                l_g[g] = l_g[g] * al + ps;
                #pragma unroll
                for (int mt = 0; mt < 4; ++mt)
                    #pragma unroll
                    for (int h = 0; h < 2; ++h)
                        upk[g][mt][h] = (u32)f2b(pv[mt * 4 + 2 * h])
                                      | ((u32)f2b(pv[mt * 4 + 2 * h + 1]) << 16);
            }
            #pragma unroll
            for (int dt = 0; dt < 8; ++dt)
                #pragma unroll
                for (int g = 0; g < 2; ++g)
                    acc[dt][g] *= alpha_g[g];
            // ---- PV: O^T += V^T * P^T
            #pragma unroll
            for (int ks = 0; ks < 2; ++ks) {
                short8 pf[2];
                #pragma unroll
                for (int g = 0; g < 2; ++g) {
                    union { u32 w[4]; short8 v; } uu;
                    #pragma unroll
                    for (int hp = 0; hp < 4; ++hp) {
                        int srcLane = l15 + 16 * ((lh & 1) * 2 + (hp >> 1));
                        u32 vA = __shfl(upk[g][2 * ks][hp & 1], srcLane, 64);
                        u32 vB = __shfl(upk[g][2 * ks + 1][hp & 1], srcLane, 64);
                        uu.w[hp] = (lh < 2) ? vA : vB;
                    }
                    pf[g] = uu.v;
                }
                #pragma unroll
                for (int dt = 0; dt < 8; ++dt) {
                    int d  = dt * 16 + l15;
                    int ch = (ks * 4 + lh) ^ (d & 7);
                    short8 av = *(const short8*)(Vb + d * 64 + ch * 8);
                    #pragma unroll
                    for (int g = 0; g < 2; ++g)
                        acc[dt][g] = __builtin_amdgcn_mfma_f32_16x16x32_bf16(
                            av, pf[g], acc[dt][g], 0, 0, 0);
                }
            }
        }
        if (have_next) writeV(cur ^ 1, vreg);     // write late, before next barrier
    }

    // ---- epilogue: raw partials
    const size_t slotrow = ((size_t)b * 32 + job) * 256 + wid * 32;
    #pragma unroll
    for (int g = 0; g < 2; ++g) {
        size_t row = slotrow + g * 16 + l15;
        #pragma unroll
        for (int dt = 0; dt < 8; ++dt) {
            ushort4 o = { f2b(acc[dt][g][0]), f2b(acc[dt][g][1]),
                          f2b(acc[dt][g][2]), f2b(acc[dt][g][3]) };
            *(ushort4*)(pO + row * 128 + dt * 16 + lh * 4) = o;
        }
        if (lh == 0) {
            pM[row] = m_g[g];
            pL[row] = l_g[g];
        }
    }
}

// ---------------------------------------------------------------------------
// merge v2: combine <=8 chunk partials per q-row.
// 2048 blocks x 256 thr; block = 8 rows, thread = 4 d-cols of one row.
// All loads independent + vectorized; one float4 store per thread.
// ---------------------------------------------------------------------------
__device__ const int g_cnt[8] = {1, 2, 3, 4, 4, 5, 6, 7};
__device__ const int g_s0[8]  = {0, 1, 3, 6, 10, 14, 19, 25};

__global__ __launch_bounds__(256)
void merge_kernel(const u16* __restrict__ pO, const float* __restrict__ pM,
                  const float* __restrict__ pL, float* __restrict__ out)
{
    const int bid = blockIdx.x;       // 0..2047
    const int b   = bid >> 8;
    const int rem = bid & 255;
    const int qi  = rem >> 5;         // 0..7
    const int rg  = rem & 31;         // rowgroup (8 rows)
    const int c = g_cnt[qi], s0 = g_s0[qi];
    const int tid = threadIdx.x;
    const int r8 = tid >> 5;          // 0..7 row within group
    const int dg = tid & 31;          // 0..31 -> d = dg*4

    const int row = rg * 8 + r8;      // within 256-row q-tile
    const size_t base = ((size_t)b * 32 + s0) * 256 + row;

    float mv[8];
    float M = NEGINF;
    #pragma unroll
    for (int i = 0; i < 8; ++i)
        if (i < c) { mv[i] = pM[base + (size_t)i * 256]; M = fmaxf(M, mv[i]); }
    float L = 0.f, w[8];
    #pragma unroll
    for (int i = 0; i < 8; ++i)
        if (i < c) {
            float e = __expf(mv[i] - M);
            L += pL[base + (size_t)i * 256] * e;
            w[i] = e;
        }
    const float invL = 1.f / L;

    float4 o = {0.f, 0.f, 0.f, 0.f};
    #pragma unroll
    for (int i = 0; i < 8; ++i)
        if (i < c) {
            ushort4 p = *(const ushort4*)(pO + (base + (size_t)i * 256) * 128 + dg * 4);
            float wi = w[i] * invL;
            o.x = fmaf(wi, b2f(p.x), o.x);
            o.y = fmaf(wi, b2f(p.y), o.y);
            o.z = fmaf(wi, b2f(p.z), o.z);
            o.w = fmaf(wi, b2f(p.w), o.w);
        }
    *(float4*)(out + ((size_t)b * Tn + qi * 256 + row) * Kn + dg * 4) = o;
}

// ---------------------------------------------------------------------------
extern "C" void kernel_launch(void* const* d_in, const int* in_sizes, int n_in,
                              void* d_out, int out_size, void* d_ws, size_t ws_size,
                              hipStream_t stream)
{
    const float* x  = (const float*)d_in[0];
    const float* Wq = (const float*)d_in[1];
    const float* Wk = (const float*)d_in[2];
    const float* Wv = (const float*)d_in[3];
    float* out = (float*)d_out;

    u16* ws = (u16*)d_ws;
    const size_t btk = (size_t)Bn * Tn * Kn;       // 2,097,152
    u16* q  = ws;
    u16* k  = ws + btk;
    u16* v  = ws + 2 * btk;
    u16* Wt = ws + 3 * btk;                        // 3*128*1024 = 393216 u16
    u16* pO = ws + 3 * btk + 393216;               // 8*32*256*128 = 8,388,608 u16
    float* pM = (float*)(pO + (size_t)8388608);    // 65536 f32
    float* pL = pM + 65536;                        // 65536 f32
    // total ws usage ~30.7 MB

    prep_kernel<<<384, 256, 0, stream>>>(Wq, Wk, Wv, Wt);
    proj_kernel<<<384, 256, 0, stream>>>(x, Wt, ws);
    attn_kernel<<<dim3(Bn, 32), 512, 0, stream>>>(q, k, v, pO, pM, pL);
    merge_kernel<<<2048, 256, 0, stream>>>(pO, pM, pL, out);
}